// Round 9
// baseline (138.079 us; speedup 1.0000x reference)
//
#include <hip/hip_runtime.h>
#include <hip/hip_bf16.h>

// Problem constants
#define BB 2
#define NN 512
#define P0 16
#define P1 32
#define P2 32
#define HH 128

typedef __attribute__((ext_vector_type(8))) short bf16x8;
typedef __attribute__((ext_vector_type(4))) float f32x4;
typedef __attribute__((ext_vector_type(4))) unsigned u32x4;

__device__ __forceinline__ unsigned pkbf(float lo, float hi) {
  __hip_bfloat162 h = __float22bfloat162_rn(float2{lo, hi});
  unsigned r;
  __builtin_memcpy(&r, &h, 4);
  return r;
}

__device__ __forceinline__ float sigm(float x) {
  return __builtin_amdgcn_rcpf(1.0f + __expf(-x));
}

__device__ __forceinline__ bf16x8 pack2(f32x4 a, f32x4 b) {
  u32x4 u;
  u[0] = pkbf(a[0], a[1]);
  u[1] = pkbf(a[2], a[3]);
  u[2] = pkbf(b[0], b[1]);
  u[3] = pkbf(b[2], b[3]);
  return __builtin_bit_cast(bf16x8, u);
}

// Monotonic uint encoding of float (works for any sign): a<b <=> enc(a)<enc(b)
__device__ __forceinline__ unsigned fenc(float f) {
  unsigned u = __float_as_uint(f);
  return (u & 0x80000000u) ? ~u : (u | 0x80000000u);
}
__device__ __forceinline__ float fdec(unsigned e) {
  unsigned u = (e & 0x80000000u) ? (e & 0x7FFFFFFFu) : ~e;
  return __uint_as_float(u);
}

// ---------------------------------------------------------------------------
// ws layout: wmax keys [2*512*32], then wmin keys [2*512*32]  (256 KiB total)
// ---------------------------------------------------------------------------
__global__ __launch_bounds__(256) void k_init(unsigned* __restrict__ w) {
  const int g = blockIdx.x * 256 + threadIdx.x;  // grid 128 -> 32768
  w[g] = 0u;                  // max identity (smallest key)
  w[32768 + g] = 0xFFFFFFFFu; // min identity (largest key)
}

// ---------------------------------------------------------------------------
// Arity-2, tile-paired: block = (b, I-tile, J-tile), 16x16 (i,j) pairs.
// out2[b,i,j,:] = mlp(concat[x2[b,i,j,:], x1[b,i,:], x2[b,j,i,:], x1[b,j,:]])
// ALL global access is >=2KB-contiguous per wave: the mirror chunk x2[b,J,I]
// (needed transposed) is staged to LDS from its natural coalesced layout —
// no 64KB-stride gathers remain (rounds 1-8's invariant suspect).
// Fused arity-1 max/min: per-tile partials + monotonic-uint atomics into ws.
// ---------------------------------------------------------------------------
__global__ __launch_bounds__(256) void k_arity2(
    const float* __restrict__ x1, const float* __restrict__ x2,
    const float* __restrict__ W1, const float* __restrict__ b1,
    const float* __restrict__ W2, const float* __restrict__ b2,
    float* __restrict__ out2, unsigned* __restrict__ wsred) {
  __shared__ __align__(16) short lw[32 * 64 * 8];  // W1 frags: 32 KiB
  __shared__ unsigned ltB[256 * 17];               // mirror chunk frags: 17 KiB
  __shared__ unsigned l1I[16 * 17], l1J[16 * 17];  // x1 tile frags

  const int tid = threadIdx.x;
  // XCD-aware swizzle (grid 2048 % 8 == 0 -> bijective)
  const int swz = (blockIdx.x & 7) * 256 + (blockIdx.x >> 3);
  const int b = swz >> 10;         // 0..1
  const int I = (swz >> 5) & 31;   // i-tile
  const int J = swz & 31;          // j-tile
  const int I0 = I * 16, J0 = J * 16;

  // --- Stage mirror chunk x2[b, J0+a, I0+c, :] (coalesced 2KB runs) ---
  // LDS key = c*16 + a (i-major) so hot-loop rows are consecutive; 17-u32 row
  // pad makes the 16 m-lane read stride 17 words -> <=2-way banking (free).
  {
    const int a = tid >> 4, c = tid & 15;
    const float* src = x2 + (((size_t)b * NN + (J0 + a)) * NN + (I0 + c)) * P2;
    unsigned* dst = &ltB[(c * 16 + a) * 17];
#pragma unroll
    for (int q = 0; q < 8; ++q) {
      const f32x4 w = *(const f32x4*)(src + 4 * q);
      dst[2 * q] = pkbf(w[0], w[1]);
      dst[2 * q + 1] = pkbf(w[2], w[3]);
    }
  }
  // --- Stage x1 tiles (rows I0.., J0..) as packed frags ---
  if (tid < 32) {
    const int isJ = tid >> 4, row = tid & 15;
    const float* src = x1 + ((size_t)b * NN + (isJ ? J0 : I0) + row) * P1;
    unsigned* dst = (isJ ? l1J : l1I) + row * 17;
#pragma unroll
    for (int q = 0; q < 8; ++q) {
      const f32x4 w = *(const f32x4*)(src + 4 * q);
      dst[2 * q] = pkbf(w[0], w[1]);
      dst[2 * q + 1] = pkbf(w[2], w[3]);
    }
  }

  // --- Stage W1 fragments (pre-swizzled to MFMA fragment order) ---
  for (int c = tid; c < 2048; c += 256) {
    const int l = c & 63, th = (c >> 6) & 7, s = c >> 9;
    const int fm = l & 15, fb = l >> 4;
    const int h = 16 * th + fm;
    float v[8];
#pragma unroll
    for (int e = 0; e < 8; ++e) {
      const int k = 32 * s + 4 * fb + (e & 3) + 16 * (e >> 2);
      v[e] = W1[k * HH + h];
    }
    unsigned* dst = (unsigned*)&lw[c * 8];
#pragma unroll
    for (int t = 0; t < 4; ++t) dst[t] = pkbf(v[2 * t], v[2 * t + 1]);
  }

  const int lane = tid & 63;
  const int wv = tid >> 6;
  const int m = lane & 15, bq = lane >> 4;

  // W2^T fragments in registers: A2[p][h], p = 16*pt + m
  bf16x8 w2f[2][4];
#pragma unroll
  for (int pt = 0; pt < 2; ++pt) {
#pragma unroll
    for (int s = 0; s < 4; ++s) {
      const int p = 16 * pt + m;
      float v[8];
#pragma unroll
      for (int e = 0; e < 8; ++e) {
        const int h = 32 * s + 4 * bq + (e & 3) + 16 * (e >> 2);
        v[e] = W2[h * P2 + p];
      }
      u32x4 u;
#pragma unroll
      for (int t = 0; t < 4; ++t) u[t] = pkbf(v[2 * t], v[2 * t + 1]);
      w2f[pt][s] = __builtin_bit_cast(bf16x8, u);
    }
  }

  f32x4 bias1[8];
#pragma unroll
  for (int th = 0; th < 8; ++th)
#pragma unroll
    for (int r = 0; r < 4; ++r) bias1[th][r] = b1[16 * th + 4 * bq + r];
  f32x4 bias2[2];
#pragma unroll
  for (int pt = 0; pt < 2; ++pt)
#pragma unroll
    for (int r = 0; r < 4; ++r) bias2[pt][r] = b2[16 * pt + 4 * bq + r];

  __syncthreads();

  const bf16x8* wl = (const bf16x8*)lw;

  // Hot loop: per (it, wv): ii fixed, lanes m = jj. 4 iterations cover ii 0..15.
#pragma unroll
  for (int it = 0; it < 4; ++it) {
    const int ii = it * 4 + wv;
    const int i = I0 + ii;
    const int j = J0 + m;

    // Direct row x2[b,i,j,:] — 2KB contiguous per wave
    const float* p0 = x2 + (((size_t)b * NN + i) * NN + j) * P2;
    const f32x4 c0a = *(const f32x4*)(p0 + 4 * bq), c0b = *(const f32x4*)(p0 + 16 + 4 * bq);

    // Fragments from LDS
    const unsigned* lr2 = &ltB[(ii * 16 + m) * 17];
    u32x4 t2;
    t2[0] = lr2[2 * bq];     t2[1] = lr2[2 * bq + 1];
    t2[2] = lr2[8 + 2 * bq]; t2[3] = lr2[9 + 2 * bq];
    const bf16x8 f2 = __builtin_bit_cast(bf16x8, t2);

    const unsigned* lr1 = &l1I[ii * 17];
    u32x4 t1;
    t1[0] = lr1[2 * bq];     t1[1] = lr1[2 * bq + 1];
    t1[2] = lr1[8 + 2 * bq]; t1[3] = lr1[9 + 2 * bq];
    const bf16x8 f1 = __builtin_bit_cast(bf16x8, t1);

    const unsigned* lr3 = &l1J[m * 17];
    u32x4 t3;
    t3[0] = lr3[2 * bq];     t3[1] = lr3[2 * bq + 1];
    t3[2] = lr3[8 + 2 * bq]; t3[3] = lr3[9 + 2 * bq];
    const bf16x8 f3 = __builtin_bit_cast(bf16x8, t3);

    const bf16x8 f0 = pack2(c0a, c0b);

    // GEMM1: D1^T[h][row]; acc[th] reg r holds h = 16*th + 4*bq + r
    f32x4 acc[8];
#pragma unroll
    for (int th = 0; th < 8; ++th)
      acc[th] = __builtin_amdgcn_mfma_f32_16x16x32_bf16(wl[(0 + th) * 64 + lane], f0, bias1[th], 0, 0, 0);
#pragma unroll
    for (int th = 0; th < 8; ++th)
      acc[th] = __builtin_amdgcn_mfma_f32_16x16x32_bf16(wl[(8 + th) * 64 + lane], f1, acc[th], 0, 0, 0);
#pragma unroll
    for (int th = 0; th < 8; ++th)
      acc[th] = __builtin_amdgcn_mfma_f32_16x16x32_bf16(wl[(16 + th) * 64 + lane], f2, acc[th], 0, 0, 0);
#pragma unroll
    for (int th = 0; th < 8; ++th)
      acc[th] = __builtin_amdgcn_mfma_f32_16x16x32_bf16(wl[(24 + th) * 64 + lane], f3, acc[th], 0, 0, 0);

    // GEMM2: out^T[p][row] = W2^T @ sigmoid(D1^T)
    f32x4 acc2[2];
#pragma unroll
    for (int pt = 0; pt < 2; ++pt) acc2[pt] = bias2[pt];
#pragma unroll
    for (int s = 0; s < 4; ++s) {
      float sv[8];
#pragma unroll
      for (int e = 0; e < 4; ++e) {
        sv[e] = sigm(acc[2 * s][e]);
        sv[4 + e] = sigm(acc[2 * s + 1][e]);
      }
      u32x4 u;
#pragma unroll
      for (int t = 0; t < 4; ++t) u[t] = pkbf(sv[2 * t], sv[2 * t + 1]);
      const bf16x8 bf = __builtin_bit_cast(bf16x8, u);
#pragma unroll
      for (int pt = 0; pt < 2; ++pt)
        acc2[pt] = __builtin_amdgcn_mfma_f32_16x16x32_bf16(w2f[pt][s], bf, acc2[pt], 0, 0, 0);
    }

    // Epilogue: sigmoid + store (2KB contiguous per wave)
    float* op = out2 + (((size_t)b * NN + i) * NN + j) * P2;
#pragma unroll
    for (int pt = 0; pt < 2; ++pt) {
      f32x4 o;
#pragma unroll
      for (int r = 0; r < 4; ++r) o[r] = sigm(acc2[pt][r]);
      *(f32x4*)(op + 16 * pt + 4 * bq) = o;
    }

    // Fused arity-1 partial: reduce this iteration's direct rows over jj (m),
    // diag (I==J, m==ii) contributes 0 (max) / 1 (min) per reference mask.
    if (wsred) {
      const bool dg = (I == J) && (m == ii);
      f32x4 qxa, qxb, qna, qnb;
#pragma unroll
      for (int r = 0; r < 4; ++r) {
        qxa[r] = dg ? 0.0f : c0a[r];
        qxb[r] = dg ? 0.0f : c0b[r];
        qna[r] = dg ? 1.0f : c0a[r];
        qnb[r] = dg ? 1.0f : c0b[r];
      }
#pragma unroll
      for (int msk = 1; msk < 16; msk <<= 1) {
#pragma unroll
        for (int r = 0; r < 4; ++r) {
          qxa[r] = fmaxf(qxa[r], __shfl_xor(qxa[r], msk));
          qxb[r] = fmaxf(qxb[r], __shfl_xor(qxb[r], msk));
          qna[r] = fminf(qna[r], __shfl_xor(qna[r], msk));
          qnb[r] = fminf(qnb[r], __shfl_xor(qnb[r], msk));
        }
      }
      if (m == 0) {
        unsigned* wmax = wsred;
        unsigned* wmin = wsred + 32768;
        const int base = ((b * NN) + i) * 32;
#pragma unroll
        for (int r = 0; r < 4; ++r) {
          atomicMax(&wmax[base + 4 * bq + r], fenc(qxa[r]));
          atomicMax(&wmax[base + 16 + 4 * bq + r], fenc(qxb[r]));
          atomicMin(&wmin[base + 4 * bq + r], fenc(qna[r]));
          atomicMin(&wmin[base + 16 + 4 * bq + r], fenc(qnb[r]));
        }
      }
    }
  }
}

// ---------------------------------------------------------------------------
// Arity-1 (fast): fully-reduced max/min keys come from ws; tiny MLP only.
// ---------------------------------------------------------------------------
__global__ __launch_bounds__(128) void k_arity1_fast(
    const float* __restrict__ x0, const float* __restrict__ x1,
    const unsigned* __restrict__ wsred, const float* __restrict__ W1,
    const float* __restrict__ b1, const float* __restrict__ W2,
    const float* __restrict__ b2, float* __restrict__ out1) {
  __shared__ float in1[112];
  __shared__ float hid[HH];

  const int tid = threadIdx.x;
  const int bid = blockIdx.x;  // 0..1023
  const int b = bid >> 9, i = bid & 511;

  if (tid < 32) {
    const int base = (b * NN + i) * 32;
    in1[tid] = x1[((size_t)b * NN + i) * P1 + tid];
    in1[48 + tid] = fdec(wsred[base + tid]);
    in1[80 + tid] = fdec(wsred[32768 + base + tid]);
  } else if (tid < 48) {
    in1[tid] = x0[b * P0 + (tid - 32)];
  }
  __syncthreads();

  {
    float s = b1[tid];
    for (int k = 0; k < 112; ++k) s += in1[k] * W1[k * HH + tid];
    hid[tid] = sigm(s);
  }
  __syncthreads();

  if (tid < 32) {
    float s = b2[tid];
    for (int k = 0; k < 128; ++k) s += hid[k] * W2[k * P1 + tid];
    out1[((size_t)b * NN + i) * P1 + tid] = sigm(s);
  }
}

// ---------------------------------------------------------------------------
// Arity-1 (fallback, full x2 scan) — used only if ws is too small.
// ---------------------------------------------------------------------------
__global__ __launch_bounds__(256) void k_arity1(
    const float* __restrict__ x0, const float* __restrict__ x1,
    const float* __restrict__ x2, const float* __restrict__ W1,
    const float* __restrict__ b1, const float* __restrict__ W2,
    const float* __restrict__ b2, float* __restrict__ out1) {
  __shared__ float rmx[8][32], rmn[8][32];
  __shared__ float in1[112];
  __shared__ float hid[128];

  const int tid = threadIdx.x;
  const int bid = blockIdx.x;  // 0..1023
  const int b = bid >> 9, i = bid & 511;
  const int p = tid & 31, jg = tid >> 5;

  const float* base = x2 + (((size_t)b * NN + i) * NN) * P2;
  float mx = 0.0f, mn = 1.0f;
  for (int j = jg; j < NN; j += 8) {
    const float v = base[(size_t)j * P2 + p];
    mx = fmaxf(mx, (j == i) ? 0.0f : v);
    mn = fminf(mn, (j == i) ? 1.0f : v);
  }
  rmx[jg][p] = mx;
  rmn[jg][p] = mn;
  __syncthreads();

  if (tid < 32) {
    float a = rmx[0][tid], c = rmn[0][tid];
#pragma unroll
    for (int g = 1; g < 8; ++g) {
      a = fmaxf(a, rmx[g][tid]);
      c = fminf(c, rmn[g][tid]);
    }
    in1[tid] = x1[((size_t)b * NN + i) * P1 + tid];
    in1[48 + tid] = a;
    in1[80 + tid] = c;
  } else if (tid < 48) {
    in1[tid] = x0[b * P0 + (tid - 32)];
  }
  __syncthreads();

  if (tid < 128) {
    float s = b1[tid];
    for (int k = 0; k < 112; ++k) s += in1[k] * W1[k * HH + tid];
    hid[tid] = sigm(s);
  }
  __syncthreads();

  if (tid < 32) {
    float s = b2[tid];
    for (int k = 0; k < 128; ++k) s += hid[k] * W2[k * P1 + tid];
    out1[((size_t)b * NN + i) * P1 + tid] = sigm(s);
  }
}

// ---------------------------------------------------------------------------
// Arity-0
// ---------------------------------------------------------------------------
__global__ __launch_bounds__(256) void k_arity0(
    const float* __restrict__ x0, const float* __restrict__ x1,
    const float* __restrict__ W1, const float* __restrict__ b1,
    const float* __restrict__ W2, const float* __restrict__ b2,
    float* __restrict__ out0) {
  __shared__ float rmx[8][32], rmn[8][32];
  __shared__ float in0[80];
  __shared__ float hid[128];

  const int tid = threadIdx.x;
  const int b = blockIdx.x;  // 0..1
  const int p = tid & 31, jg = tid >> 5;

  float mx = -1e30f, mn = 1e30f;
  for (int j = jg; j < NN; j += 8) {
    const float v = x1[((size_t)b * NN + j) * P1 + p];
    mx = fmaxf(mx, v);
    mn = fminf(mn, v);
  }
  rmx[jg][p] = mx;
  rmn[jg][p] = mn;
  __syncthreads();

  if (tid < 32) {
    float a = rmx[0][tid], c = rmn[0][tid];
#pragma unroll
    for (int g = 1; g < 8; ++g) {
      a = fmaxf(a, rmx[g][tid]);
      c = fminf(c, rmn[g][tid]);
    }
    in0[16 + tid] = a;
    in0[48 + tid] = c;
  } else if (tid < 48) {
    in0[tid - 32] = x0[b * P0 + (tid - 32)];
  }
  __syncthreads();

  if (tid < 128) {
    float s = b1[tid];
    for (int k = 0; k < 80; ++k) s += in0[k] * W1[k * HH + tid];
    hid[tid] = sigm(s);
  }
  __syncthreads();

  if (tid < 16) {
    float s = b2[tid];
    for (int k = 0; k < 128; ++k) s += hid[k] * W2[k * P0 + tid];
    out0[b * P0 + tid] = sigm(s);
  }
}

extern "C" void kernel_launch(void* const* d_in, const int* in_sizes, int n_in,
                              void* d_out, int out_size, void* d_ws, size_t ws_size,
                              hipStream_t stream) {
  const float* x0   = (const float*)d_in[0];
  const float* x1   = (const float*)d_in[1];
  const float* x2   = (const float*)d_in[2];
  const float* W1_0 = (const float*)d_in[3];
  const float* b1_0 = (const float*)d_in[4];
  const float* W2_0 = (const float*)d_in[5];
  const float* b2_0 = (const float*)d_in[6];
  const float* W1_1 = (const float*)d_in[7];
  const float* b1_1 = (const float*)d_in[8];
  const float* W2_1 = (const float*)d_in[9];
  const float* b2_1 = (const float*)d_in[10];
  const float* W1_2 = (const float*)d_in[11];
  const float* b1_2 = (const float*)d_in[12];
  const float* W2_2 = (const float*)d_in[13];
  const float* b2_2 = (const float*)d_in[14];

  float* out0 = (float*)d_out;
  float* out1 = out0 + (size_t)BB * P0;
  float* out2 = out1 + (size_t)BB * NN * P1;

  const bool use_ws = ws_size >= (size_t)2 * 32768 * sizeof(unsigned);  // 256 KiB
  unsigned* wsred = use_ws ? (unsigned*)d_ws : nullptr;

  if (use_ws) {
    hipLaunchKernelGGL(k_init, dim3(128), dim3(256), 0, stream, wsred);
  }
  hipLaunchKernelGGL(k_arity2, dim3(2048), dim3(256), 0, stream,
                     x1, x2, W1_2, b1_2, W2_2, b2_2, out2, wsred);
  if (use_ws) {
    hipLaunchKernelGGL(k_arity1_fast, dim3(1024), dim3(128), 0, stream,
                       x0, x1, wsred, W1_1, b1_1, W2_1, b2_1, out1);
  } else {
    hipLaunchKernelGGL(k_arity1, dim3(1024), dim3(256), 0, stream,
                       x0, x1, x2, W1_1, b1_1, W2_1, b2_1, out1);
  }
  hipLaunchKernelGGL(k_arity0, dim3(2), dim3(256), 0, stream,
                     x0, x1, W1_0, b1_0, W2_0, b2_0, out0);
}

// Round 10
// 99.883 us; speedup vs baseline: 1.3824x; 1.3824x over previous
//
#include <hip/hip_runtime.h>
#include <hip/hip_bf16.h>

// Problem constants
#define BB 2
#define NN 512
#define P0 16
#define P1 32
#define P2 32
#define HH 128

typedef __attribute__((ext_vector_type(8))) short bf16x8;
typedef __attribute__((ext_vector_type(4))) float f32x4;
typedef __attribute__((ext_vector_type(4))) unsigned u32x4;

__device__ __forceinline__ unsigned pkbf(float lo, float hi) {
  __hip_bfloat162 h = __float22bfloat162_rn(float2{lo, hi});
  unsigned r;
  __builtin_memcpy(&r, &h, 4);
  return r;
}

__device__ __forceinline__ float sigm(float x) {
  return __builtin_amdgcn_rcpf(1.0f + __expf(-x));
}

__device__ __forceinline__ bf16x8 pack2(f32x4 a, f32x4 b) {
  u32x4 u;
  u[0] = pkbf(a[0], a[1]);
  u[1] = pkbf(a[2], a[3]);
  u[2] = pkbf(b[0], b[1]);
  u[3] = pkbf(b[2], b[3]);
  return __builtin_bit_cast(bf16x8, u);
}

// ---------------------------------------------------------------------------
// Arity-2, PAIRED: block (b,i) processes pairs (i, j) for j = i+1..i+256
// (mod 512) and computes BOTH out(i,j) and out(j,i) from the same four
// fragments {x2_ij, x1_i, x2_ji, x1_j} (W1-slice roles swapped). Per-output
// loads/packs/addressing halve; mirror GEMM is pure-register compute.
// Pair {i,i+256} is computed by two blocks identically (benign). Diagonal
// handled by k_diag. MLP: 128 ->(sigm) 128 ->(sigm) 32, bf16 MFMA 16x16x32.
// ---------------------------------------------------------------------------
__global__ __launch_bounds__(256) void k_arity2(
    const float* __restrict__ x1, const float* __restrict__ x2,
    const float* __restrict__ W1, const float* __restrict__ b1,
    const float* __restrict__ W2, const float* __restrict__ b2,
    float* __restrict__ out2) {
  __shared__ __align__(16) short lw[32 * 64 * 8];  // W1 frags: 32 KiB

  const int tid = threadIdx.x;
  const int bid = blockIdx.x;  // 0..1023
  const int b = bid >> 9;      // 0..1
  const int i = bid & 511;     // 0..511

  // Stage W1 fragments to LDS (pre-swizzled to MFMA fragment order).
  for (int c = tid; c < 2048; c += 256) {
    const int l = c & 63, th = (c >> 6) & 7, s = c >> 9;
    const int fm = l & 15, fb = l >> 4;
    const int h = 16 * th + fm;
    float v[8];
#pragma unroll
    for (int e = 0; e < 8; ++e) {
      const int k = 32 * s + 4 * fb + (e & 3) + 16 * (e >> 2);
      v[e] = W1[k * HH + h];
    }
    unsigned* dst = (unsigned*)&lw[c * 8];
#pragma unroll
    for (int t = 0; t < 4; ++t) dst[t] = pkbf(v[2 * t], v[2 * t + 1]);
  }

  const int lane = tid & 63;
  const int wv = tid >> 6;
  const int m = lane & 15, bq = lane >> 4;

  // W2^T fragments in registers: A2[p][h], p = 16*pt + m
  bf16x8 w2f[2][4];
#pragma unroll
  for (int pt = 0; pt < 2; ++pt) {
#pragma unroll
    for (int s = 0; s < 4; ++s) {
      const int p = 16 * pt + m;
      float v[8];
#pragma unroll
      for (int e = 0; e < 8; ++e) {
        const int h = 32 * s + 4 * bq + (e & 3) + 16 * (e >> 2);
        v[e] = W2[h * P2 + p];
      }
      u32x4 u;
#pragma unroll
      for (int t = 0; t < 4; ++t) u[t] = pkbf(v[2 * t], v[2 * t + 1]);
      w2f[pt][s] = __builtin_bit_cast(bf16x8, u);
    }
  }

  f32x4 bias1[8];
#pragma unroll
  for (int th = 0; th < 8; ++th)
#pragma unroll
    for (int r = 0; r < 4; ++r) bias1[th][r] = b1[16 * th + 4 * bq + r];
  f32x4 bias2[2];
#pragma unroll
  for (int pt = 0; pt < 2; ++pt)
#pragma unroll
    for (int r = 0; r < 4; ++r) bias2[pt][r] = b2[16 * pt + 4 * bq + r];

  // x1[b,i,:] fragment, constant over the block
  const float* x1bi = x1 + ((size_t)b * NN + i) * P1;
  const bf16x8 f1 = pack2(*(const f32x4*)(x1bi + 4 * bq),
                          *(const f32x4*)(x1bi + 16 + 4 * bq));

  __syncthreads();

  const bf16x8* wl = (const bf16x8*)lw;
  const size_t rowI = (size_t)b * NN + i;

#pragma unroll
  for (int it = 0; it < 4; ++it) {
    const int j = (i + 1 + it * 64 + wv * 16 + m) & 511;

    const float* p0 = x2 + (rowI * NN + j) * P2;                  // x2[b,i,j,:]
    const float* p2 = x2 + (((size_t)b * NN + j) * NN + i) * P2;  // x2[b,j,i,:]
    const float* p3 = x1 + ((size_t)b * NN + j) * P1;             // x1[b,j,:]
    const f32x4 c0a = *(const f32x4*)(p0 + 4 * bq), c0b = *(const f32x4*)(p0 + 16 + 4 * bq);
    const f32x4 c2a = *(const f32x4*)(p2 + 4 * bq), c2b = *(const f32x4*)(p2 + 16 + 4 * bq);
    const f32x4 c3a = *(const f32x4*)(p3 + 4 * bq), c3b = *(const f32x4*)(p3 + 16 + 4 * bq);

    const bf16x8 f0 = pack2(c0a, c0b);
    const bf16x8 f2 = pack2(c2a, c2b);
    const bf16x8 f3 = pack2(c3a, c3b);

    // ---- DIRECT: out(i,j); in = [f0, f1, f2, f3] ----
    {
      f32x4 acc[8];
#pragma unroll
      for (int th = 0; th < 8; ++th)
        acc[th] = __builtin_amdgcn_mfma_f32_16x16x32_bf16(wl[(0 + th) * 64 + lane], f0, bias1[th], 0, 0, 0);
#pragma unroll
      for (int th = 0; th < 8; ++th)
        acc[th] = __builtin_amdgcn_mfma_f32_16x16x32_bf16(wl[(8 + th) * 64 + lane], f1, acc[th], 0, 0, 0);
#pragma unroll
      for (int th = 0; th < 8; ++th)
        acc[th] = __builtin_amdgcn_mfma_f32_16x16x32_bf16(wl[(16 + th) * 64 + lane], f2, acc[th], 0, 0, 0);
#pragma unroll
      for (int th = 0; th < 8; ++th)
        acc[th] = __builtin_amdgcn_mfma_f32_16x16x32_bf16(wl[(24 + th) * 64 + lane], f3, acc[th], 0, 0, 0);

      f32x4 acc2[2];
#pragma unroll
      for (int pt = 0; pt < 2; ++pt) acc2[pt] = bias2[pt];
#pragma unroll
      for (int s = 0; s < 4; ++s) {
        float sv[8];
#pragma unroll
        for (int e = 0; e < 4; ++e) {
          sv[e] = sigm(acc[2 * s][e]);
          sv[4 + e] = sigm(acc[2 * s + 1][e]);
        }
        u32x4 u;
#pragma unroll
        for (int t = 0; t < 4; ++t) u[t] = pkbf(sv[2 * t], sv[2 * t + 1]);
        const bf16x8 bf = __builtin_bit_cast(bf16x8, u);
#pragma unroll
        for (int pt = 0; pt < 2; ++pt)
          acc2[pt] = __builtin_amdgcn_mfma_f32_16x16x32_bf16(w2f[pt][s], bf, acc2[pt], 0, 0, 0);
      }

      float* op = out2 + (rowI * NN + j) * P2;
#pragma unroll
      for (int pt = 0; pt < 2; ++pt) {
        f32x4 o;
#pragma unroll
        for (int r = 0; r < 4; ++r) o[r] = sigm(acc2[pt][r]);
        *(f32x4*)(op + 16 * pt + 4 * bq) = o;
      }
    }

    // ---- MIRROR: out(j,i); in = [f2, f3, f0, f1] (pure-register compute) ----
    {
      f32x4 acc[8];
#pragma unroll
      for (int th = 0; th < 8; ++th)
        acc[th] = __builtin_amdgcn_mfma_f32_16x16x32_bf16(wl[(0 + th) * 64 + lane], f2, bias1[th], 0, 0, 0);
#pragma unroll
      for (int th = 0; th < 8; ++th)
        acc[th] = __builtin_amdgcn_mfma_f32_16x16x32_bf16(wl[(8 + th) * 64 + lane], f3, acc[th], 0, 0, 0);
#pragma unroll
      for (int th = 0; th < 8; ++th)
        acc[th] = __builtin_amdgcn_mfma_f32_16x16x32_bf16(wl[(16 + th) * 64 + lane], f0, acc[th], 0, 0, 0);
#pragma unroll
      for (int th = 0; th < 8; ++th)
        acc[th] = __builtin_amdgcn_mfma_f32_16x16x32_bf16(wl[(24 + th) * 64 + lane], f1, acc[th], 0, 0, 0);

      f32x4 acc2[2];
#pragma unroll
      for (int pt = 0; pt < 2; ++pt) acc2[pt] = bias2[pt];
#pragma unroll
      for (int s = 0; s < 4; ++s) {
        float sv[8];
#pragma unroll
        for (int e = 0; e < 4; ++e) {
          sv[e] = sigm(acc[2 * s][e]);
          sv[4 + e] = sigm(acc[2 * s + 1][e]);
        }
        u32x4 u;
#pragma unroll
        for (int t = 0; t < 4; ++t) u[t] = pkbf(sv[2 * t], sv[2 * t + 1]);
        const bf16x8 bf = __builtin_bit_cast(bf16x8, u);
#pragma unroll
        for (int pt = 0; pt < 2; ++pt)
          acc2[pt] = __builtin_amdgcn_mfma_f32_16x16x32_bf16(w2f[pt][s], bf, acc2[pt], 0, 0, 0);
      }

      float* op = out2 + (((size_t)b * NN + j) * NN + i) * P2;  // scattered rows
#pragma unroll
      for (int pt = 0; pt < 2; ++pt) {
        f32x4 o;
#pragma unroll
        for (int r = 0; r < 4; ++r) o[r] = sigm(acc2[pt][r]);
        *(f32x4*)(op + 16 * pt + 4 * bq) = o;
      }
    }
  }
}

// ---------------------------------------------------------------------------
// Diagonal: out2[b,i,i,:] = mlp([x2_ii, x1_i, x2_ii, x1_i])
// ---------------------------------------------------------------------------
__global__ __launch_bounds__(128) void k_diag(
    const float* __restrict__ x1, const float* __restrict__ x2,
    const float* __restrict__ W1, const float* __restrict__ b1,
    const float* __restrict__ W2, const float* __restrict__ b2,
    float* __restrict__ out2) {
  __shared__ float in2[128];
  __shared__ float hid[128];

  const int tid = threadIdx.x;
  const int bid = blockIdx.x;  // 0..1023
  const int b = bid >> 9, i = bid & 511;

  const int q = tid & 63;
  const float v = (q < 32) ? x2[(((size_t)b * NN + i) * NN + i) * P2 + q]
                           : x1[((size_t)b * NN + i) * P1 + (q - 32)];
  in2[tid] = v;  // positions 64..127 repeat 0..63
  __syncthreads();

  {
    float s = b1[tid];
    for (int k = 0; k < 128; ++k) s += in2[k] * W1[k * HH + tid];
    hid[tid] = sigm(s);
  }
  __syncthreads();

  if (tid < 32) {
    float s = b2[tid];
    for (int k = 0; k < 128; ++k) s += hid[k] * W2[k * P2 + tid];
    out2[(((size_t)b * NN + i) * NN + i) * P2 + tid] = sigm(s);
  }
}

// ---------------------------------------------------------------------------
// Arity-1 (standalone, vectorized rescan): per (b,i) reduce x2[b,i,:,:] with
// f32x4 reads (L3-resident), then the tiny MLP.
// ---------------------------------------------------------------------------
__global__ __launch_bounds__(256) void k_arity1(
    const float* __restrict__ x0, const float* __restrict__ x1,
    const float* __restrict__ x2, const float* __restrict__ W1,
    const float* __restrict__ b1, const float* __restrict__ W2,
    const float* __restrict__ b2, float* __restrict__ out1) {
  __shared__ float rmx[32][32], rmn[32][32];  // [j-group][channel]
  __shared__ float in1[112];
  __shared__ float hid[128];

  const int tid = threadIdx.x;
  const int bid = blockIdx.x;  // 0..1023
  const int b = bid >> 9, i = bid & 511;
  const int q = tid & 7;    // channel quad (channels 4q..4q+3)
  const int jg = tid >> 3;  // 0..31

  const float* base = x2 + (((size_t)b * NN + i) * NN) * P2 + 4 * q;
  f32x4 mx = {0.f, 0.f, 0.f, 0.f}, mn = {1.f, 1.f, 1.f, 1.f};
  for (int j = jg; j < NN; j += 32) {
    const f32x4 v = *(const f32x4*)(base + (size_t)j * P2);
    const bool dg = (j == i);
#pragma unroll
    for (int r = 0; r < 4; ++r) {
      mx[r] = fmaxf(mx[r], dg ? 0.0f : v[r]);
      mn[r] = fminf(mn[r], dg ? 1.0f : v[r]);
    }
  }
#pragma unroll
  for (int r = 0; r < 4; ++r) {
    rmx[jg][4 * q + r] = mx[r];
    rmn[jg][4 * q + r] = mn[r];
  }
  __syncthreads();

  if (tid < 32) {
    float a = rmx[0][tid], c = rmn[0][tid];
#pragma unroll
    for (int g = 1; g < 32; ++g) {
      a = fmaxf(a, rmx[g][tid]);
      c = fminf(c, rmn[g][tid]);
    }
    in1[tid] = x1[((size_t)b * NN + i) * P1 + tid];
    in1[48 + tid] = a;
    in1[80 + tid] = c;
  } else if (tid < 48) {
    in1[tid] = x0[b * P0 + (tid - 32)];
  }
  __syncthreads();

  if (tid < 128) {
    float s = b1[tid];
    for (int k = 0; k < 112; ++k) s += in1[k] * W1[k * HH + tid];
    hid[tid] = sigm(s);
  }
  __syncthreads();

  if (tid < 32) {
    float s = b2[tid];
    for (int k = 0; k < 128; ++k) s += hid[k] * W2[k * P1 + tid];
    out1[((size_t)b * NN + i) * P1 + tid] = sigm(s);
  }
}

// ---------------------------------------------------------------------------
// Arity-0
// ---------------------------------------------------------------------------
__global__ __launch_bounds__(256) void k_arity0(
    const float* __restrict__ x0, const float* __restrict__ x1,
    const float* __restrict__ W1, const float* __restrict__ b1,
    const float* __restrict__ W2, const float* __restrict__ b2,
    float* __restrict__ out0) {
  __shared__ float rmx[8][32], rmn[8][32];
  __shared__ float in0[80];
  __shared__ float hid[128];

  const int tid = threadIdx.x;
  const int b = blockIdx.x;  // 0..1
  const int p = tid & 31, jg = tid >> 5;

  float mx = -1e30f, mn = 1e30f;
  for (int j = jg; j < NN; j += 8) {
    const float v = x1[((size_t)b * NN + j) * P1 + p];
    mx = fmaxf(mx, v);
    mn = fminf(mn, v);
  }
  rmx[jg][p] = mx;
  rmn[jg][p] = mn;
  __syncthreads();

  if (tid < 32) {
    float a = rmx[0][tid], c = rmn[0][tid];
#pragma unroll
    for (int g = 1; g < 8; ++g) {
      a = fmaxf(a, rmx[g][tid]);
      c = fminf(c, rmn[g][tid]);
    }
    in0[16 + tid] = a;
    in0[48 + tid] = c;
  } else if (tid < 48) {
    in0[tid - 32] = x0[b * P0 + (tid - 32)];
  }
  __syncthreads();

  if (tid < 128) {
    float s = b1[tid];
    for (int k = 0; k < 80; ++k) s += in0[k] * W1[k * HH + tid];
    hid[tid] = sigm(s);
  }
  __syncthreads();

  if (tid < 16) {
    float s = b2[tid];
    for (int k = 0; k < 128; ++k) s += hid[k] * W2[k * P0 + tid];
    out0[b * P0 + tid] = sigm(s);
  }
}

extern "C" void kernel_launch(void* const* d_in, const int* in_sizes, int n_in,
                              void* d_out, int out_size, void* d_ws, size_t ws_size,
                              hipStream_t stream) {
  const float* x0   = (const float*)d_in[0];
  const float* x1   = (const float*)d_in[1];
  const float* x2   = (const float*)d_in[2];
  const float* W1_0 = (const float*)d_in[3];
  const float* b1_0 = (const float*)d_in[4];
  const float* W2_0 = (const float*)d_in[5];
  const float* b2_0 = (const float*)d_in[6];
  const float* W1_1 = (const float*)d_in[7];
  const float* b1_1 = (const float*)d_in[8];
  const float* W2_1 = (const float*)d_in[9];
  const float* b2_1 = (const float*)d_in[10];
  const float* W1_2 = (const float*)d_in[11];
  const float* b1_2 = (const float*)d_in[12];
  const float* W2_2 = (const float*)d_in[13];
  const float* b2_2 = (const float*)d_in[14];

  float* out0 = (float*)d_out;
  float* out1 = out0 + (size_t)BB * P0;
  float* out2 = out1 + (size_t)BB * NN * P1;

  hipLaunchKernelGGL(k_arity2, dim3(1024), dim3(256), 0, stream,
                     x1, x2, W1_2, b1_2, W2_2, b2_2, out2);
  hipLaunchKernelGGL(k_diag, dim3(1024), dim3(128), 0, stream,
                     x1, x2, W1_2, b1_2, W2_2, b2_2, out2);
  hipLaunchKernelGGL(k_arity1, dim3(1024), dim3(256), 0, stream,
                     x0, x1, x2, W1_1, b1_1, W2_1, b2_1, out1);
  hipLaunchKernelGGL(k_arity0, dim3(2), dim3(256), 0, stream,
                     x0, x1, W1_0, b1_0, W2_0, b2_0, out0);
}

// Round 11
// 84.711 us; speedup vs baseline: 1.6300x; 1.1791x over previous
//
#include <hip/hip_runtime.h>
#include <hip/hip_bf16.h>

// Problem constants
#define BB 2
#define NN 512
#define P0 16
#define P1 32
#define P2 32
#define HH 128

typedef __attribute__((ext_vector_type(8))) short bf16x8;
typedef __attribute__((ext_vector_type(4))) float f32x4;
typedef __attribute__((ext_vector_type(4))) unsigned u32x4;

__device__ __forceinline__ unsigned pkbf(float lo, float hi) {
  __hip_bfloat162 h = __float22bfloat162_rn(float2{lo, hi});
  unsigned r;
  __builtin_memcpy(&r, &h, 4);
  return r;
}

__device__ __forceinline__ float sigm(float x) {
  return __builtin_amdgcn_rcpf(1.0f + __expf(-x));
}

__device__ __forceinline__ bf16x8 pack2(f32x4 a, f32x4 b) {
  u32x4 u;
  u[0] = pkbf(a[0], a[1]);
  u[1] = pkbf(a[2], a[3]);
  u[2] = pkbf(b[0], b[1]);
  u[3] = pkbf(b[2], b[3]);
  return __builtin_bit_cast(bf16x8, u);
}

// ---------------------------------------------------------------------------
// Arity-2, PAIRED (round-10 win: 80->65us, FETCH halved) + re-fused arity-1
// reduction. Block (b,i): pairs (i,j), j = i+1..i+256 (ring), computes BOTH
// out(i,j) and out(j,i) from the shared fragments {x2_ij, x1_i, x2_ji, x1_j}.
// Reduction completeness: direct rows give j in i+1..i+256; extra
// reduction-only reads of x2[b,i,j+256,:] give i+257..i+512==i (diagonal
// masked 0/1) -> every j exactly once -> complete in-block max/min -> wsred
// (plain stores, deterministic). Diagonal MLP + arity-1 MLP fused in k_post.
// ---------------------------------------------------------------------------
__global__ __launch_bounds__(256) void k_arity2(
    const float* __restrict__ x1, const float* __restrict__ x2,
    const float* __restrict__ W1, const float* __restrict__ b1,
    const float* __restrict__ W2, const float* __restrict__ b2,
    float* __restrict__ out2, float* __restrict__ wsred) {
  __shared__ __align__(16) short lw[32 * 64 * 8];  // W1 frags: 32 KiB
  __shared__ float pm[4][32], pn[4][32];           // reduction partials: 1 KiB

  const int tid = threadIdx.x;
  const int bid = blockIdx.x;  // 0..1023
  const int b = bid >> 9;      // 0..1
  const int i = bid & 511;     // 0..511

  // Stage W1 fragments to LDS (pre-swizzled to MFMA fragment order).
  for (int c = tid; c < 2048; c += 256) {
    const int l = c & 63, th = (c >> 6) & 7, s = c >> 9;
    const int fm = l & 15, fb = l >> 4;
    const int h = 16 * th + fm;
    float v[8];
#pragma unroll
    for (int e = 0; e < 8; ++e) {
      const int k = 32 * s + 4 * fb + (e & 3) + 16 * (e >> 2);
      v[e] = W1[k * HH + h];
    }
    unsigned* dst = (unsigned*)&lw[c * 8];
#pragma unroll
    for (int t = 0; t < 4; ++t) dst[t] = pkbf(v[2 * t], v[2 * t + 1]);
  }

  const int lane = tid & 63;
  const int wv = tid >> 6;
  const int m = lane & 15, bq = lane >> 4;

  // W2^T fragments in registers: A2[p][h], p = 16*pt + m
  bf16x8 w2f[2][4];
#pragma unroll
  for (int pt = 0; pt < 2; ++pt) {
#pragma unroll
    for (int s = 0; s < 4; ++s) {
      const int p = 16 * pt + m;
      float v[8];
#pragma unroll
      for (int e = 0; e < 8; ++e) {
        const int h = 32 * s + 4 * bq + (e & 3) + 16 * (e >> 2);
        v[e] = W2[h * P2 + p];
      }
      u32x4 u;
#pragma unroll
      for (int t = 0; t < 4; ++t) u[t] = pkbf(v[2 * t], v[2 * t + 1]);
      w2f[pt][s] = __builtin_bit_cast(bf16x8, u);
    }
  }

  f32x4 bias1[8];
#pragma unroll
  for (int th = 0; th < 8; ++th)
#pragma unroll
    for (int r = 0; r < 4; ++r) bias1[th][r] = b1[16 * th + 4 * bq + r];
  f32x4 bias2[2];
#pragma unroll
  for (int pt = 0; pt < 2; ++pt)
#pragma unroll
    for (int r = 0; r < 4; ++r) bias2[pt][r] = b2[16 * pt + 4 * bq + r];

  // x1[b,i,:] fragment, constant over the block
  const float* x1bi = x1 + ((size_t)b * NN + i) * P1;
  const bf16x8 f1 = pack2(*(const f32x4*)(x1bi + 4 * bq),
                          *(const f32x4*)(x1bi + 16 + 4 * bq));

  __syncthreads();

  const bf16x8* wl = (const bf16x8*)lw;
  const size_t rowI = (size_t)b * NN + i;

  // Fused arity-1 reduction partials (channels 4bq..4bq+3 and 16+4bq..).
  f32x4 pmx0 = {0.f, 0.f, 0.f, 0.f}, pmx1 = {0.f, 0.f, 0.f, 0.f};
  f32x4 pmn0 = {1.f, 1.f, 1.f, 1.f}, pmn1 = {1.f, 1.f, 1.f, 1.f};

#pragma unroll
  for (int it = 0; it < 4; ++it) {
    const int j = (i + 1 + it * 64 + wv * 16 + m) & 511;
    const int j2 = (j + 256) & 511;  // other-half row for reduction only

    const float* p0 = x2 + (rowI * NN + j) * P2;                  // x2[b,i,j,:]
    const float* p2 = x2 + (((size_t)b * NN + j) * NN + i) * P2;  // x2[b,j,i,:]
    const float* p3 = x1 + ((size_t)b * NN + j) * P1;             // x1[b,j,:]
    const float* p4 = x2 + (rowI * NN + j2) * P2;                 // x2[b,i,j2,:]
    const f32x4 c0a = *(const f32x4*)(p0 + 4 * bq), c0b = *(const f32x4*)(p0 + 16 + 4 * bq);
    const f32x4 c2a = *(const f32x4*)(p2 + 4 * bq), c2b = *(const f32x4*)(p2 + 16 + 4 * bq);
    const f32x4 c3a = *(const f32x4*)(p3 + 4 * bq), c3b = *(const f32x4*)(p3 + 16 + 4 * bq);
    const f32x4 c4a = *(const f32x4*)(p4 + 4 * bq), c4b = *(const f32x4*)(p4 + 16 + 4 * bq);

    // Reduction: c0 (j in ring, never diagonal) unconditional; c4 masked at
    // j2 == i (diagonal contributes 0 to max / 1 to min, per reference).
    {
      const bool dg = (j2 == i);
#pragma unroll
      for (int r = 0; r < 4; ++r) {
        pmx0[r] = fmaxf(pmx0[r], fmaxf(c0a[r], dg ? 0.0f : c4a[r]));
        pmx1[r] = fmaxf(pmx1[r], fmaxf(c0b[r], dg ? 0.0f : c4b[r]));
        pmn0[r] = fminf(pmn0[r], fminf(c0a[r], dg ? 1.0f : c4a[r]));
        pmn1[r] = fminf(pmn1[r], fminf(c0b[r], dg ? 1.0f : c4b[r]));
      }
    }

    const bf16x8 f0 = pack2(c0a, c0b);
    const bf16x8 f2 = pack2(c2a, c2b);
    const bf16x8 f3 = pack2(c3a, c3b);

    // ---- DIRECT: out(i,j); in = [f0, f1, f2, f3] ----
    {
      f32x4 acc[8];
#pragma unroll
      for (int th = 0; th < 8; ++th)
        acc[th] = __builtin_amdgcn_mfma_f32_16x16x32_bf16(wl[(0 + th) * 64 + lane], f0, bias1[th], 0, 0, 0);
#pragma unroll
      for (int th = 0; th < 8; ++th)
        acc[th] = __builtin_amdgcn_mfma_f32_16x16x32_bf16(wl[(8 + th) * 64 + lane], f1, acc[th], 0, 0, 0);
#pragma unroll
      for (int th = 0; th < 8; ++th)
        acc[th] = __builtin_amdgcn_mfma_f32_16x16x32_bf16(wl[(16 + th) * 64 + lane], f2, acc[th], 0, 0, 0);
#pragma unroll
      for (int th = 0; th < 8; ++th)
        acc[th] = __builtin_amdgcn_mfma_f32_16x16x32_bf16(wl[(24 + th) * 64 + lane], f3, acc[th], 0, 0, 0);

      f32x4 acc2[2];
#pragma unroll
      for (int pt = 0; pt < 2; ++pt) acc2[pt] = bias2[pt];
#pragma unroll
      for (int s = 0; s < 4; ++s) {
        float sv[8];
#pragma unroll
        for (int e = 0; e < 4; ++e) {
          sv[e] = sigm(acc[2 * s][e]);
          sv[4 + e] = sigm(acc[2 * s + 1][e]);
        }
        u32x4 u;
#pragma unroll
        for (int t = 0; t < 4; ++t) u[t] = pkbf(sv[2 * t], sv[2 * t + 1]);
        const bf16x8 bf = __builtin_bit_cast(bf16x8, u);
#pragma unroll
        for (int pt = 0; pt < 2; ++pt)
          acc2[pt] = __builtin_amdgcn_mfma_f32_16x16x32_bf16(w2f[pt][s], bf, acc2[pt], 0, 0, 0);
      }

      float* op = out2 + (rowI * NN + j) * P2;
#pragma unroll
      for (int pt = 0; pt < 2; ++pt) {
        f32x4 o;
#pragma unroll
        for (int r = 0; r < 4; ++r) o[r] = sigm(acc2[pt][r]);
        *(f32x4*)(op + 16 * pt + 4 * bq) = o;
      }
    }

    // ---- MIRROR: out(j,i); in = [f2, f3, f0, f1] (pure-register compute) ----
    {
      f32x4 acc[8];
#pragma unroll
      for (int th = 0; th < 8; ++th)
        acc[th] = __builtin_amdgcn_mfma_f32_16x16x32_bf16(wl[(0 + th) * 64 + lane], f2, bias1[th], 0, 0, 0);
#pragma unroll
      for (int th = 0; th < 8; ++th)
        acc[th] = __builtin_amdgcn_mfma_f32_16x16x32_bf16(wl[(8 + th) * 64 + lane], f3, acc[th], 0, 0, 0);
#pragma unroll
      for (int th = 0; th < 8; ++th)
        acc[th] = __builtin_amdgcn_mfma_f32_16x16x32_bf16(wl[(16 + th) * 64 + lane], f0, acc[th], 0, 0, 0);
#pragma unroll
      for (int th = 0; th < 8; ++th)
        acc[th] = __builtin_amdgcn_mfma_f32_16x16x32_bf16(wl[(24 + th) * 64 + lane], f1, acc[th], 0, 0, 0);

      f32x4 acc2[2];
#pragma unroll
      for (int pt = 0; pt < 2; ++pt) acc2[pt] = bias2[pt];
#pragma unroll
      for (int s = 0; s < 4; ++s) {
        float sv[8];
#pragma unroll
        for (int e = 0; e < 4; ++e) {
          sv[e] = sigm(acc[2 * s][e]);
          sv[4 + e] = sigm(acc[2 * s + 1][e]);
        }
        u32x4 u;
#pragma unroll
        for (int t = 0; t < 4; ++t) u[t] = pkbf(sv[2 * t], sv[2 * t + 1]);
        const bf16x8 bf = __builtin_bit_cast(bf16x8, u);
#pragma unroll
        for (int pt = 0; pt < 2; ++pt)
          acc2[pt] = __builtin_amdgcn_mfma_f32_16x16x32_bf16(w2f[pt][s], bf, acc2[pt], 0, 0, 0);
      }

      float* op = out2 + (((size_t)b * NN + j) * NN + i) * P2;
#pragma unroll
      for (int pt = 0; pt < 2; ++pt) {
        f32x4 o;
#pragma unroll
        for (int r = 0; r < 4; ++r) o[r] = sigm(acc2[pt][r]);
        *(f32x4*)(op + 16 * pt + 4 * bq) = o;
      }
    }
  }

  // Finish complete reduction: butterfly over 16 m-lanes, combine 4 waves,
  // write 64 floats (32 max, 32 min) per (b,i). Plain stores: deterministic.
  if (wsred) {
#pragma unroll
    for (int msk = 1; msk < 16; msk <<= 1) {
#pragma unroll
      for (int r = 0; r < 4; ++r) {
        pmx0[r] = fmaxf(pmx0[r], __shfl_xor(pmx0[r], msk));
        pmx1[r] = fmaxf(pmx1[r], __shfl_xor(pmx1[r], msk));
        pmn0[r] = fminf(pmn0[r], __shfl_xor(pmn0[r], msk));
        pmn1[r] = fminf(pmn1[r], __shfl_xor(pmn1[r], msk));
      }
    }
    if (m == 0) {
#pragma unroll
      for (int r = 0; r < 4; ++r) {
        pm[wv][4 * bq + r] = pmx0[r];  pm[wv][16 + 4 * bq + r] = pmx1[r];
        pn[wv][4 * bq + r] = pmn0[r];  pn[wv][16 + 4 * bq + r] = pmn1[r];
      }
    }
    __syncthreads();
    if (tid < 32) {
      float a = pm[0][tid], c = pn[0][tid];
#pragma unroll
      for (int g = 1; g < 4; ++g) {
        a = fmaxf(a, pm[g][tid]);
        c = fminf(c, pn[g][tid]);
      }
      const size_t o = ((size_t)b * NN + i) * 64;
      wsred[o + tid] = a;
      wsred[o + 32 + tid] = c;
    }
  }
}

// ---------------------------------------------------------------------------
// k_post: fused per-(b,i) tail — arity-1 MLP (reduction from wsred) AND the
// arity-2 diagonal out2[b,i,i,:] = mlp([x2_ii, x1_i, x2_ii, x1_i]).
// ---------------------------------------------------------------------------
__global__ __launch_bounds__(128) void k_post(
    const float* __restrict__ x0, const float* __restrict__ x1,
    const float* __restrict__ x2, const float* __restrict__ wsred,
    const float* __restrict__ W1_1, const float* __restrict__ b1_1,
    const float* __restrict__ W2_1, const float* __restrict__ b2_1,
    const float* __restrict__ W1_2, const float* __restrict__ b1_2,
    const float* __restrict__ W2_2, const float* __restrict__ b2_2,
    float* __restrict__ out1, float* __restrict__ out2) {
  __shared__ float in1[112], in2[128];
  __shared__ float hid1[HH], hid2[HH];

  const int tid = threadIdx.x;
  const int bid = blockIdx.x;  // 0..1023
  const int b = bid >> 9, i = bid & 511;
  const size_t o = ((size_t)b * NN + i) * 64;

  if (tid < 32) {
    in1[tid] = x1[((size_t)b * NN + i) * P1 + tid];
    in1[48 + tid] = wsred[o + tid];
    in1[80 + tid] = wsred[o + 32 + tid];
  } else if (tid < 48) {
    in1[tid] = x0[b * P0 + (tid - 32)];
  }
  {
    const int q = tid & 63;
    in2[tid] = (q < 32) ? x2[(((size_t)b * NN + i) * NN + i) * P2 + q]
                        : x1[((size_t)b * NN + i) * P1 + (q - 32)];
  }
  __syncthreads();

  {
    float s1 = b1_1[tid];
    for (int k = 0; k < 112; ++k) s1 += in1[k] * W1_1[k * HH + tid];
    hid1[tid] = sigm(s1);
    float s2 = b1_2[tid];
    for (int k = 0; k < 128; ++k) s2 += in2[k] * W1_2[k * HH + tid];
    hid2[tid] = sigm(s2);
  }
  __syncthreads();

  if (tid < 32) {
    float t1 = b2_1[tid];
    for (int k = 0; k < 128; ++k) t1 += hid1[k] * W2_1[k * P1 + tid];
    out1[((size_t)b * NN + i) * P1 + tid] = sigm(t1);
    float t2 = b2_2[tid];
    for (int k = 0; k < 128; ++k) t2 += hid2[k] * W2_2[k * P2 + tid];
    out2[(((size_t)b * NN + i) * NN + i) * P2 + tid] = sigm(t2);
  }
}

// ---------------------------------------------------------------------------
// Fallbacks (used only if ws too small): standalone arity-1 rescan + diag.
// ---------------------------------------------------------------------------
__global__ __launch_bounds__(256) void k_arity1(
    const float* __restrict__ x0, const float* __restrict__ x1,
    const float* __restrict__ x2, const float* __restrict__ W1,
    const float* __restrict__ b1, const float* __restrict__ W2,
    const float* __restrict__ b2, float* __restrict__ out1) {
  __shared__ float rmx[8][32], rmn[8][32];
  __shared__ float in1[112];
  __shared__ float hid[128];

  const int tid = threadIdx.x;
  const int bid = blockIdx.x;
  const int b = bid >> 9, i = bid & 511;
  const int p = tid & 31, jg = tid >> 5;

  const float* base = x2 + (((size_t)b * NN + i) * NN) * P2;
  float mx = 0.0f, mn = 1.0f;
  for (int j = jg; j < NN; j += 8) {
    const float v = base[(size_t)j * P2 + p];
    mx = fmaxf(mx, (j == i) ? 0.0f : v);
    mn = fminf(mn, (j == i) ? 1.0f : v);
  }
  rmx[jg][p] = mx;
  rmn[jg][p] = mn;
  __syncthreads();

  if (tid < 32) {
    float a = rmx[0][tid], c = rmn[0][tid];
#pragma unroll
    for (int g = 1; g < 8; ++g) {
      a = fmaxf(a, rmx[g][tid]);
      c = fminf(c, rmn[g][tid]);
    }
    in1[tid] = x1[((size_t)b * NN + i) * P1 + tid];
    in1[48 + tid] = a;
    in1[80 + tid] = c;
  } else if (tid < 48) {
    in1[tid] = x0[b * P0 + (tid - 32)];
  }
  __syncthreads();

  if (tid < 128) {
    float s = b1[tid];
    for (int k = 0; k < 112; ++k) s += in1[k] * W1[k * HH + tid];
    hid[tid] = sigm(s);
  }
  __syncthreads();

  if (tid < 32) {
    float s = b2[tid];
    for (int k = 0; k < 128; ++k) s += hid[k] * W2[k * P1 + tid];
    out1[((size_t)b * NN + i) * P1 + tid] = sigm(s);
  }
}

__global__ __launch_bounds__(128) void k_diag(
    const float* __restrict__ x1, const float* __restrict__ x2,
    const float* __restrict__ W1, const float* __restrict__ b1,
    const float* __restrict__ W2, const float* __restrict__ b2,
    float* __restrict__ out2) {
  __shared__ float in2[128];
  __shared__ float hid[128];

  const int tid = threadIdx.x;
  const int bid = blockIdx.x;
  const int b = bid >> 9, i = bid & 511;

  const int q = tid & 63;
  in2[tid] = (q < 32) ? x2[(((size_t)b * NN + i) * NN + i) * P2 + q]
                      : x1[((size_t)b * NN + i) * P1 + (q - 32)];
  __syncthreads();

  {
    float s = b1[tid];
    for (int k = 0; k < 128; ++k) s += in2[k] * W1[k * HH + tid];
    hid[tid] = sigm(s);
  }
  __syncthreads();

  if (tid < 32) {
    float s = b2[tid];
    for (int k = 0; k < 128; ++k) s += hid[k] * W2[k * P2 + tid];
    out2[(((size_t)b * NN + i) * NN + i) * P2 + tid] = sigm(s);
  }
}

// ---------------------------------------------------------------------------
// Arity-0
// ---------------------------------------------------------------------------
__global__ __launch_bounds__(256) void k_arity0(
    const float* __restrict__ x0, const float* __restrict__ x1,
    const float* __restrict__ W1, const float* __restrict__ b1,
    const float* __restrict__ W2, const float* __restrict__ b2,
    float* __restrict__ out0) {
  __shared__ float rmx[8][32], rmn[8][32];
  __shared__ float in0[80];
  __shared__ float hid[128];

  const int tid = threadIdx.x;
  const int b = blockIdx.x;  // 0..1
  const int p = tid & 31, jg = tid >> 5;

  float mx = -1e30f, mn = 1e30f;
  for (int j = jg; j < NN; j += 8) {
    const float v = x1[((size_t)b * NN + j) * P1 + p];
    mx = fmaxf(mx, v);
    mn = fminf(mn, v);
  }
  rmx[jg][p] = mx;
  rmn[jg][p] = mn;
  __syncthreads();

  if (tid < 32) {
    float a = rmx[0][tid], c = rmn[0][tid];
#pragma unroll
    for (int g = 1; g < 8; ++g) {
      a = fmaxf(a, rmx[g][tid]);
      c = fminf(c, rmn[g][tid]);
    }
    in0[16 + tid] = a;
    in0[48 + tid] = c;
  } else if (tid < 48) {
    in0[tid - 32] = x0[b * P0 + (tid - 32)];
  }
  __syncthreads();

  if (tid < 128) {
    float s = b1[tid];
    for (int k = 0; k < 80; ++k) s += in0[k] * W1[k * HH + tid];
    hid[tid] = sigm(s);
  }
  __syncthreads();

  if (tid < 16) {
    float s = b2[tid];
    for (int k = 0; k < 128; ++k) s += hid[k] * W2[k * P0 + tid];
    out0[b * P0 + tid] = sigm(s);
  }
}

extern "C" void kernel_launch(void* const* d_in, const int* in_sizes, int n_in,
                              void* d_out, int out_size, void* d_ws, size_t ws_size,
                              hipStream_t stream) {
  const float* x0   = (const float*)d_in[0];
  const float* x1   = (const float*)d_in[1];
  const float* x2   = (const float*)d_in[2];
  const float* W1_0 = (const float*)d_in[3];
  const float* b1_0 = (const float*)d_in[4];
  const float* W2_0 = (const float*)d_in[5];
  const float* b2_0 = (const float*)d_in[6];
  const float* W1_1 = (const float*)d_in[7];
  const float* b1_1 = (const float*)d_in[8];
  const float* W2_1 = (const float*)d_in[9];
  const float* b2_1 = (const float*)d_in[10];
  const float* W1_2 = (const float*)d_in[11];
  const float* b1_2 = (const float*)d_in[12];
  const float* W2_2 = (const float*)d_in[13];
  const float* b2_2 = (const float*)d_in[14];

  float* out0 = (float*)d_out;
  float* out1 = out0 + (size_t)BB * P0;
  float* out2 = out1 + (size_t)BB * NN * P1;

  const bool use_ws = ws_size >= (size_t)BB * NN * 64 * sizeof(float);  // 256 KiB
  float* wsred = use_ws ? (float*)d_ws : nullptr;

  hipLaunchKernelGGL(k_arity2, dim3(1024), dim3(256), 0, stream,
                     x1, x2, W1_2, b1_2, W2_2, b2_2, out2, wsred);
  if (use_ws) {
    hipLaunchKernelGGL(k_post, dim3(1024), dim3(128), 0, stream,
                       x0, x1, x2, wsred,
                       W1_1, b1_1, W2_1, b2_1,
                       W1_2, b1_2, W2_2, b2_2,
                       out1, out2);
  } else {
    hipLaunchKernelGGL(k_arity1, dim3(1024), dim3(256), 0, stream,
                       x0, x1, x2, W1_1, b1_1, W2_1, b2_1, out1);
    hipLaunchKernelGGL(k_diag, dim3(1024), dim3(128), 0, stream,
                       x1, x2, W1_2, b1_2, W2_2, b2_2, out2);
  }
  hipLaunchKernelGGL(k_arity0, dim3(2), dim3(256), 0, stream,
                     x0, x1, W1_0, b1_0, W2_0, b2_0, out0);
}

// Round 12
// 82.248 us; speedup vs baseline: 1.6788x; 1.0300x over previous
//
#include <hip/hip_runtime.h>
#include <hip/hip_bf16.h>

// Problem constants
#define BB 2
#define NN 512
#define P0 16
#define P1 32
#define P2 32
#define HH 128

typedef __attribute__((ext_vector_type(8))) short bf16x8;
typedef __attribute__((ext_vector_type(4))) float f32x4;
typedef __attribute__((ext_vector_type(4))) unsigned u32x4;

__device__ __forceinline__ unsigned pkbf(float lo, float hi) {
  __hip_bfloat162 h = __float22bfloat162_rn(float2{lo, hi});
  unsigned r;
  __builtin_memcpy(&r, &h, 4);
  return r;
}

__device__ __forceinline__ float sigm(float x) {
  return __builtin_amdgcn_rcpf(1.0f + __expf(-x));
}

__device__ __forceinline__ bf16x8 pack2(f32x4 a, f32x4 b) {
  u32x4 u;
  u[0] = pkbf(a[0], a[1]);
  u[1] = pkbf(a[2], a[3]);
  u[2] = pkbf(b[0], b[1]);
  u[3] = pkbf(b[2], b[3]);
  return __builtin_bit_cast(bf16x8, u);
}

// ---------------------------------------------------------------------------
// Arity-2, PAIRED + fully-fused tail. Block (b,i):
//  * pairs (i,j), j = i+1..i+256 (ring): computes out(i,j) AND out(j,i) from
//    shared fragments {x2_ij, x1_i, x2_ji, x1_j} (W1-slice roles swapped).
//  * complete arity-1 max/min reduction in-block (direct rows + other-half
//    reduction-only reads; diagonal masked 0/1).
//  * block epilogue: arity-1 MLP (out1[b,i,:]) and the arity-2 diagonal
//    out2[b,i,i,:] — no second kernel, no workspace.
// MLP: 128 ->(sigm) 128 ->(sigm) 32, bf16 MFMA 16x16x32, transposed GEMMs.
// NOTE: plain __launch_bounds__(256) — (256,4) caused 64-VGPR scratch spill.
// ---------------------------------------------------------------------------
__global__ __launch_bounds__(256) void k_arity2(
    const float* __restrict__ x0, const float* __restrict__ x1,
    const float* __restrict__ x2,
    const float* __restrict__ W1, const float* __restrict__ b1,
    const float* __restrict__ W2, const float* __restrict__ b2,
    const float* __restrict__ W1_1, const float* __restrict__ b1_1,
    const float* __restrict__ W2_1, const float* __restrict__ b2_1,
    float* __restrict__ out1, float* __restrict__ out2) {
  __shared__ __align__(16) short lw[32 * 64 * 8];  // W1 frags: 32 KiB
  __shared__ float pm[4][32], pn[4][32];           // reduction partials
  __shared__ float in1[112], in2[128];             // tail MLP inputs
  __shared__ float hid1[HH], hid2[HH];             // tail hidden layers

  const int tid = threadIdx.x;
  const int bid = blockIdx.x;  // 0..1023
  const int b = bid >> 9;      // 0..1
  const int i = bid & 511;     // 0..511

  // Stage W1 fragments to LDS (pre-swizzled to MFMA fragment order).
  for (int c = tid; c < 2048; c += 256) {
    const int l = c & 63, th = (c >> 6) & 7, s = c >> 9;
    const int fm = l & 15, fb = l >> 4;
    const int h = 16 * th + fm;
    float v[8];
#pragma unroll
    for (int e = 0; e < 8; ++e) {
      const int k = 32 * s + 4 * fb + (e & 3) + 16 * (e >> 2);
      v[e] = W1[k * HH + h];
    }
    unsigned* dst = (unsigned*)&lw[c * 8];
#pragma unroll
    for (int t = 0; t < 4; ++t) dst[t] = pkbf(v[2 * t], v[2 * t + 1]);
  }

  const int lane = tid & 63;
  const int wv = tid >> 6;
  const int m = lane & 15, bq = lane >> 4;

  // W2^T fragments in registers: A2[p][h], p = 16*pt + m
  bf16x8 w2f[2][4];
#pragma unroll
  for (int pt = 0; pt < 2; ++pt) {
#pragma unroll
    for (int s = 0; s < 4; ++s) {
      const int p = 16 * pt + m;
      float v[8];
#pragma unroll
      for (int e = 0; e < 8; ++e) {
        const int h = 32 * s + 4 * bq + (e & 3) + 16 * (e >> 2);
        v[e] = W2[h * P2 + p];
      }
      u32x4 u;
#pragma unroll
      for (int t = 0; t < 4; ++t) u[t] = pkbf(v[2 * t], v[2 * t + 1]);
      w2f[pt][s] = __builtin_bit_cast(bf16x8, u);
    }
  }

  f32x4 bias1[8];
#pragma unroll
  for (int th = 0; th < 8; ++th)
#pragma unroll
    for (int r = 0; r < 4; ++r) bias1[th][r] = b1[16 * th + 4 * bq + r];
  f32x4 bias2[2];
#pragma unroll
  for (int pt = 0; pt < 2; ++pt)
#pragma unroll
    for (int r = 0; r < 4; ++r) bias2[pt][r] = b2[16 * pt + 4 * bq + r];

  // x1[b,i,:] fragment, constant over the block
  const float* x1bi = x1 + ((size_t)b * NN + i) * P1;
  const bf16x8 f1 = pack2(*(const f32x4*)(x1bi + 4 * bq),
                          *(const f32x4*)(x1bi + 16 + 4 * bq));

  __syncthreads();

  const bf16x8* wl = (const bf16x8*)lw;
  const size_t rowI = (size_t)b * NN + i;

  // Fused arity-1 reduction partials (channels 4bq..4bq+3 and 16+4bq..).
  f32x4 pmx0 = {0.f, 0.f, 0.f, 0.f}, pmx1 = {0.f, 0.f, 0.f, 0.f};
  f32x4 pmn0 = {1.f, 1.f, 1.f, 1.f}, pmn1 = {1.f, 1.f, 1.f, 1.f};

#pragma unroll
  for (int it = 0; it < 4; ++it) {
    const int j = (i + 1 + it * 64 + wv * 16 + m) & 511;
    const int j2 = (j + 256) & 511;  // other-half row for reduction only

    const float* p0 = x2 + (rowI * NN + j) * P2;                  // x2[b,i,j,:]
    const float* p2 = x2 + (((size_t)b * NN + j) * NN + i) * P2;  // x2[b,j,i,:]
    const float* p3 = x1 + ((size_t)b * NN + j) * P1;             // x1[b,j,:]
    const float* p4 = x2 + (rowI * NN + j2) * P2;                 // x2[b,i,j2,:]
    const f32x4 c0a = *(const f32x4*)(p0 + 4 * bq), c0b = *(const f32x4*)(p0 + 16 + 4 * bq);
    const f32x4 c2a = *(const f32x4*)(p2 + 4 * bq), c2b = *(const f32x4*)(p2 + 16 + 4 * bq);
    const f32x4 c3a = *(const f32x4*)(p3 + 4 * bq), c3b = *(const f32x4*)(p3 + 16 + 4 * bq);
    const f32x4 c4a = *(const f32x4*)(p4 + 4 * bq), c4b = *(const f32x4*)(p4 + 16 + 4 * bq);

    // Reduction: c0 (ring j, never diagonal) unconditional; c4 masked at j2==i.
    {
      const bool dg = (j2 == i);
#pragma unroll
      for (int r = 0; r < 4; ++r) {
        pmx0[r] = fmaxf(pmx0[r], fmaxf(c0a[r], dg ? 0.0f : c4a[r]));
        pmx1[r] = fmaxf(pmx1[r], fmaxf(c0b[r], dg ? 0.0f : c4b[r]));
        pmn0[r] = fminf(pmn0[r], fminf(c0a[r], dg ? 1.0f : c4a[r]));
        pmn1[r] = fminf(pmn1[r], fminf(c0b[r], dg ? 1.0f : c4b[r]));
      }
    }

    const bf16x8 f0 = pack2(c0a, c0b);
    const bf16x8 f2 = pack2(c2a, c2b);
    const bf16x8 f3 = pack2(c3a, c3b);

    // ---- DIRECT: out(i,j); in = [f0, f1, f2, f3] ----
    {
      f32x4 acc[8];
#pragma unroll
      for (int th = 0; th < 8; ++th)
        acc[th] = __builtin_amdgcn_mfma_f32_16x16x32_bf16(wl[(0 + th) * 64 + lane], f0, bias1[th], 0, 0, 0);
#pragma unroll
      for (int th = 0; th < 8; ++th)
        acc[th] = __builtin_amdgcn_mfma_f32_16x16x32_bf16(wl[(8 + th) * 64 + lane], f1, acc[th], 0, 0, 0);
#pragma unroll
      for (int th = 0; th < 8; ++th)
        acc[th] = __builtin_amdgcn_mfma_f32_16x16x32_bf16(wl[(16 + th) * 64 + lane], f2, acc[th], 0, 0, 0);
#pragma unroll
      for (int th = 0; th < 8; ++th)
        acc[th] = __builtin_amdgcn_mfma_f32_16x16x32_bf16(wl[(24 + th) * 64 + lane], f3, acc[th], 0, 0, 0);

      f32x4 acc2[2];
#pragma unroll
      for (int pt = 0; pt < 2; ++pt) acc2[pt] = bias2[pt];
#pragma unroll
      for (int s = 0; s < 4; ++s) {
        float sv[8];
#pragma unroll
        for (int e = 0; e < 4; ++e) {
          sv[e] = sigm(acc[2 * s][e]);
          sv[4 + e] = sigm(acc[2 * s + 1][e]);
        }
        u32x4 u;
#pragma unroll
        for (int t = 0; t < 4; ++t) u[t] = pkbf(sv[2 * t], sv[2 * t + 1]);
        const bf16x8 bf = __builtin_bit_cast(bf16x8, u);
#pragma unroll
        for (int pt = 0; pt < 2; ++pt)
          acc2[pt] = __builtin_amdgcn_mfma_f32_16x16x32_bf16(w2f[pt][s], bf, acc2[pt], 0, 0, 0);
      }

      float* op = out2 + (rowI * NN + j) * P2;
#pragma unroll
      for (int pt = 0; pt < 2; ++pt) {
        f32x4 o;
#pragma unroll
        for (int r = 0; r < 4; ++r) o[r] = sigm(acc2[pt][r]);
        *(f32x4*)(op + 16 * pt + 4 * bq) = o;
      }
    }

    // ---- MIRROR: out(j,i); in = [f2, f3, f0, f1] (pure-register compute) ----
    {
      f32x4 acc[8];
#pragma unroll
      for (int th = 0; th < 8; ++th)
        acc[th] = __builtin_amdgcn_mfma_f32_16x16x32_bf16(wl[(0 + th) * 64 + lane], f2, bias1[th], 0, 0, 0);
#pragma unroll
      for (int th = 0; th < 8; ++th)
        acc[th] = __builtin_amdgcn_mfma_f32_16x16x32_bf16(wl[(8 + th) * 64 + lane], f3, acc[th], 0, 0, 0);
#pragma unroll
      for (int th = 0; th < 8; ++th)
        acc[th] = __builtin_amdgcn_mfma_f32_16x16x32_bf16(wl[(16 + th) * 64 + lane], f0, acc[th], 0, 0, 0);
#pragma unroll
      for (int th = 0; th < 8; ++th)
        acc[th] = __builtin_amdgcn_mfma_f32_16x16x32_bf16(wl[(24 + th) * 64 + lane], f1, acc[th], 0, 0, 0);

      f32x4 acc2[2];
#pragma unroll
      for (int pt = 0; pt < 2; ++pt) acc2[pt] = bias2[pt];
#pragma unroll
      for (int s = 0; s < 4; ++s) {
        float sv[8];
#pragma unroll
        for (int e = 0; e < 4; ++e) {
          sv[e] = sigm(acc[2 * s][e]);
          sv[4 + e] = sigm(acc[2 * s + 1][e]);
        }
        u32x4 u;
#pragma unroll
        for (int t = 0; t < 4; ++t) u[t] = pkbf(sv[2 * t], sv[2 * t + 1]);
        const bf16x8 bf = __builtin_bit_cast(bf16x8, u);
#pragma unroll
        for (int pt = 0; pt < 2; ++pt)
          acc2[pt] = __builtin_amdgcn_mfma_f32_16x16x32_bf16(w2f[pt][s], bf, acc2[pt], 0, 0, 0);
      }

      float* op = out2 + (((size_t)b * NN + j) * NN + i) * P2;
#pragma unroll
      for (int pt = 0; pt < 2; ++pt) {
        f32x4 o;
#pragma unroll
        for (int r = 0; r < 4; ++r) o[r] = sigm(acc2[pt][r]);
        *(f32x4*)(op + 16 * pt + 4 * bq) = o;
      }
    }
  }

  // ---- Complete the reduction in LDS ----
#pragma unroll
  for (int msk = 1; msk < 16; msk <<= 1) {
#pragma unroll
    for (int r = 0; r < 4; ++r) {
      pmx0[r] = fmaxf(pmx0[r], __shfl_xor(pmx0[r], msk));
      pmx1[r] = fmaxf(pmx1[r], __shfl_xor(pmx1[r], msk));
      pmn0[r] = fminf(pmn0[r], __shfl_xor(pmn0[r], msk));
      pmn1[r] = fminf(pmn1[r], __shfl_xor(pmn1[r], msk));
    }
  }
  if (m == 0) {
#pragma unroll
    for (int r = 0; r < 4; ++r) {
      pm[wv][4 * bq + r] = pmx0[r];  pm[wv][16 + 4 * bq + r] = pmx1[r];
      pn[wv][4 * bq + r] = pmn0[r];  pn[wv][16 + 4 * bq + r] = pmn1[r];
    }
  }
  // Fill diagonal-MLP input while the reduction partials settle.
  if (tid >= 64 && tid < 128) {
    const int q = tid - 64;
    const float v = (q < 32) ? x2[(rowI * NN + i) * P2 + q] : x1bi[q - 32];
    in2[q] = v;
    in2[64 + q] = v;
  }
  __syncthreads();

  // ---- Fused tail: arity-1 MLP input assembly ----
  if (tid < 32) {
    float a = pm[0][tid], c = pn[0][tid];
#pragma unroll
    for (int g = 1; g < 4; ++g) {
      a = fmaxf(a, pm[g][tid]);
      c = fminf(c, pn[g][tid]);
    }
    in1[tid] = x1bi[tid];
    in1[48 + tid] = a;
    in1[80 + tid] = c;
  } else if (tid < 48) {
    in1[tid] = x0[b * P0 + (tid - 32)];
  }
  __syncthreads();

  // Hidden layers: tid<128 -> arity-1 (112 in), tid>=128 -> diagonal (128 in).
  if (tid < 128) {
    float s = b1_1[tid];
    for (int k = 0; k < 112; ++k) s += in1[k] * W1_1[k * HH + tid];
    hid1[tid] = sigm(s);
  } else {
    const int h = tid - 128;
    float s = b1[h];
    for (int k = 0; k < 128; ++k) s += in2[k] * W1[k * HH + h];
    hid2[h] = sigm(s);
  }
  __syncthreads();

  // Output layers.
  if (tid < 32) {
    float s = b2_1[tid];
    for (int k = 0; k < 128; ++k) s += hid1[k] * W2_1[k * P1 + tid];
    out1[rowI * P1 + tid] = sigm(s);
  } else if (tid >= 128 && tid < 160) {
    const int p = tid - 128;
    float s = b2[p];
    for (int k = 0; k < 128; ++k) s += hid2[k] * W2[k * P2 + p];
    out2[(rowI * NN + i) * P2 + p] = sigm(s);
  }
}

// ---------------------------------------------------------------------------
// Arity-0
// ---------------------------------------------------------------------------
__global__ __launch_bounds__(256) void k_arity0(
    const float* __restrict__ x0, const float* __restrict__ x1,
    const float* __restrict__ W1, const float* __restrict__ b1,
    const float* __restrict__ W2, const float* __restrict__ b2,
    float* __restrict__ out0) {
  __shared__ float rmx[8][32], rmn[8][32];
  __shared__ float in0[80];
  __shared__ float hid[128];

  const int tid = threadIdx.x;
  const int b = blockIdx.x;  // 0..1
  const int p = tid & 31, jg = tid >> 5;

  float mx = -1e30f, mn = 1e30f;
  for (int j = jg; j < NN; j += 8) {
    const float v = x1[((size_t)b * NN + j) * P1 + p];
    mx = fmaxf(mx, v);
    mn = fminf(mn, v);
  }
  rmx[jg][p] = mx;
  rmn[jg][p] = mn;
  __syncthreads();

  if (tid < 32) {
    float a = rmx[0][tid], c = rmn[0][tid];
#pragma unroll
    for (int g = 1; g < 8; ++g) {
      a = fmaxf(a, rmx[g][tid]);
      c = fminf(c, rmn[g][tid]);
    }
    in0[16 + tid] = a;
    in0[48 + tid] = c;
  } else if (tid < 48) {
    in0[tid - 32] = x0[b * P0 + (tid - 32)];
  }
  __syncthreads();

  if (tid < 128) {
    float s = b1[tid];
    for (int k = 0; k < 80; ++k) s += in0[k] * W1[k * HH + tid];
    hid[tid] = sigm(s);
  }
  __syncthreads();

  if (tid < 16) {
    float s = b2[tid];
    for (int k = 0; k < 128; ++k) s += hid[k] * W2[k * P0 + tid];
    out0[b * P0 + tid] = sigm(s);
  }
}

extern "C" void kernel_launch(void* const* d_in, const int* in_sizes, int n_in,
                              void* d_out, int out_size, void* d_ws, size_t ws_size,
                              hipStream_t stream) {
  const float* x0   = (const float*)d_in[0];
  const float* x1   = (const float*)d_in[1];
  const float* x2   = (const float*)d_in[2];
  const float* W1_0 = (const float*)d_in[3];
  const float* b1_0 = (const float*)d_in[4];
  const float* W2_0 = (const float*)d_in[5];
  const float* b2_0 = (const float*)d_in[6];
  const float* W1_1 = (const float*)d_in[7];
  const float* b1_1 = (const float*)d_in[8];
  const float* W2_1 = (const float*)d_in[9];
  const float* b2_1 = (const float*)d_in[10];
  const float* W1_2 = (const float*)d_in[11];
  const float* b1_2 = (const float*)d_in[12];
  const float* W2_2 = (const float*)d_in[13];
  const float* b2_2 = (const float*)d_in[14];

  float* out0 = (float*)d_out;
  float* out1 = out0 + (size_t)BB * P0;
  float* out2 = out1 + (size_t)BB * NN * P1;

  hipLaunchKernelGGL(k_arity2, dim3(1024), dim3(256), 0, stream,
                     x0, x1, x2, W1_2, b1_2, W2_2, b2_2,
                     W1_1, b1_1, W2_1, b2_1, out1, out2);
  hipLaunchKernelGGL(k_arity0, dim3(2), dim3(256), 0, stream,
                     x0, x1, W1_0, b1_0, W2_0, b2_0, out0);
}